// Round 1
// baseline (674.336 us; speedup 1.0000x reference)
//
#include <hip/hip_runtime.h>
#include <stdint.h>

// Problem constants (fixed by setup_inputs).
constexpr int NPTS = 8192;
constexpr int DIM  = 64;
constexpr int KNN  = 12;

// Tiling: 64x64 output tile, 4x4 per-thread micro-tile, 256 threads.
constexpr int RT = 64;               // rows per workgroup
constexpr int CT = 64;               // cols per chunk
constexpr int CS = 4;                // column splits (grid parallelism)
constexpr int STRIPE = NPTS / CS;    // 2048 cols per split
constexpr int NCHUNK = STRIPE / CT;  // 32 chunks
constexpr int AS_STRIDE = RT + 4;    // 68: keeps float4 16B-aligned, rotates banks
constexpr int BS_STRIDE = CT + 4;    // 68

constexpr unsigned long long SENTINEL = 0xFFFFFFFFFFFFFFFFull;

__global__ void init_out(float* out) {
  if (threadIdx.x < 4) out[threadIdx.x] = 0.0f;  // d_out is poisoned each call
}

// sq[i] = sum_d latent[i][d]^2
__global__ __launch_bounds__(256) void sq_kernel(const float* __restrict__ latent,
                                                 float* __restrict__ sq) {
  int i = blockIdx.x * 256 + threadIdx.x;
  const float4* p = reinterpret_cast<const float4*>(latent + (size_t)i * DIM);
  float s = 0.f;
#pragma unroll
  for (int t = 0; t < DIM / 4; ++t) {
    float4 v = p[t];
    s += v.x * v.x + v.y * v.y + v.z * v.z + v.w * v.w;
  }
  sq[i] = s;
}

// Sorted-ascending 12-list insert; cand packs (d2_bits<<32)|j so u64 compare
// == (value, index) lexicographic == JAX stable argsort order.
__device__ __forceinline__ void topk_insert(unsigned long long cand,
                                            unsigned long long pk[KNN]) {
#pragma unroll
  for (int s = KNN - 1; s >= 0; --s) {
    bool belongs = cand < pk[s];
    bool shift = (s > 0) && (cand < pk[s - 1]);
    unsigned long long nv = shift ? pk[s - 1] : cand;
    if (belongs) pk[s] = nv;
  }
}

__global__ __launch_bounds__(256, 2) void dz_main(
    const float* __restrict__ latent, const float* __restrict__ latent_norm,
    const float* __restrict__ dist_X, const float* __restrict__ mask_X,
    const float* __restrict__ sq, unsigned long long* __restrict__ topk_ws,
    float* __restrict__ d_out) {
  __shared__ float As[DIM * AS_STRIDE];       // k-major: As[k][r]
  __shared__ float Bs[DIM * BS_STRIDE];       // k-major: Bs[k][c]
  __shared__ unsigned long long buf[RT * CT]; // per-row candidate queues
  __shared__ int   cnt[RT];
  __shared__ float thr[RT];                   // running 12th-smallest d2 per row
  __shared__ float sqA[RT];
  __shared__ float sqB[CT];
  __shared__ float red[256];

  const int tid = threadIdx.x;
  const int tile = blockIdx.x / CS;
  const int split = blockIdx.x % CS;
  const int ib = tile * RT;
  const int jb0 = split * STRIPE;

  const float invnorm = 1.0f / latent_norm[0];

  // Stage A transposed (once): global coalesced (k contiguous per lane group).
#pragma unroll
  for (int i = 0; i < (RT * DIM) / 256; ++i) {
    int flat = i * 256 + tid;
    int k = flat & (DIM - 1);
    int r = flat >> 6;
    As[k * AS_STRIDE + r] = latent[(size_t)(ib + r) * DIM + k];
  }
  if (tid < RT) { sqA[tid] = sq[ib + tid]; thr[tid] = 3.4e38f; }

  unsigned long long pk[KNN];
#pragma unroll
  for (int t = 0; t < KNN; ++t) pk[t] = SENTINEL;

  const int tr = tid >> 4, tc = tid & 15;
  const int r0 = tr * 4, c0 = tc * 4;
  float acc1 = 0.f;  // distance1_2 partial

  for (int ch = 0; ch < NCHUNK; ++ch) {
    const int jb = jb0 + ch * CT;
    __syncthreads();  // (A) prev merge done; Bs / cnt safe to overwrite
#pragma unroll
    for (int i = 0; i < (CT * DIM) / 256; ++i) {
      int flat = i * 256 + tid;
      int k = flat & (DIM - 1);
      int c = flat >> 6;
      Bs[k * BS_STRIDE + c] = latent[(size_t)(jb + c) * DIM + k];
    }
    if (tid < CT) sqB[tid] = sq[jb + tid];
    if (tid < RT) cnt[tid] = 0;
    __syncthreads();  // (B)

    // Prefetch this chunk's dist_X / mask_X fragments (hidden under FMA loop).
    float4 dxv[4], mxv[4];
#pragma unroll
    for (int ri = 0; ri < 4; ++ri) {
      size_t base = (size_t)(ib + r0 + ri) * NPTS + jb + c0;
      dxv[ri] = *reinterpret_cast<const float4*>(dist_X + base);
      mxv[ri] = *reinterpret_cast<const float4*>(mask_X + base);
    }

    float acc[4][4];
#pragma unroll
    for (int a = 0; a < 4; ++a)
#pragma unroll
      for (int b = 0; b < 4; ++b) acc[a][b] = 0.f;

#pragma unroll 8
    for (int k = 0; k < DIM; ++k) {
      float4 av = *reinterpret_cast<const float4*>(&As[k * AS_STRIDE + r0]);
      float4 bv = *reinterpret_cast<const float4*>(&Bs[k * BS_STRIDE + c0]);
      float aa[4] = {av.x, av.y, av.z, av.w};
      float bb[4] = {bv.x, bv.y, bv.z, bv.w};
#pragma unroll
      for (int ri = 0; ri < 4; ++ri)
#pragma unroll
        for (int ci = 0; ci < 4; ++ci) acc[ri][ci] += aa[ri] * bb[ci];
    }

    // d2, distance1_2 accumulation, candidate push.
#pragma unroll
    for (int ri = 0; ri < 4; ++ri) {
      const int r = r0 + ri;
      const int gi = ib + r;
      const float t_thr = thr[r];
      float dxa[4] = {dxv[ri].x, dxv[ri].y, dxv[ri].z, dxv[ri].w};
      float mxa[4] = {mxv[ri].x, mxv[ri].y, mxv[ri].z, mxv[ri].w};
#pragma unroll
      for (int ci = 0; ci < 4; ++ci) {
        const int j = jb + c0 + ci;
        float d2 = sqA[r] + sqB[c0 + ci] - 2.0f * acc[ri][ci];
        float d2c = fmaxf(d2, 0.0f);
        float dz = (d2c > 0.0f) ? sqrtf(d2c) * invnorm : 0.0f;
        float diff = dxa[ci] - dz;
        acc1 += mxa[ci] * diff * diff;
        if (d2c < t_thr && j != gi) {
          int pos = atomicAdd(&cnt[r], 1);  // LDS atomic; pos < CT guaranteed
          buf[r * CT + pos] =
              ((unsigned long long)__float_as_uint(d2c) << 32) | (unsigned)j;
        }
      }
    }
    __syncthreads();  // (C) pushes visible

    if (tid < RT) {  // one thread per row merges its (rare) candidates
      int n = cnt[tid];
      for (int t = 0; t < n; ++t) {
        unsigned long long cand = buf[tid * CT + t];
        if (cand < pk[KNN - 1]) topk_insert(cand, pk);
      }
      thr[tid] = __uint_as_float((unsigned)(pk[KNN - 1] >> 32));
    }
  }

  // Per-(row,split) partial top-12 to workspace.
  if (tid < RT) {
    size_t base = ((size_t)(ib + tid) * CS + split) * KNN;
#pragma unroll
    for (int t = 0; t < KNN; ++t) topk_ws[base + t] = pk[t];
  }

  // Block-reduce distance1_2 partials.
  red[tid] = acc1;
  __syncthreads();
  for (int s = 128; s > 0; s >>= 1) {
    if (tid < s) red[tid] += red[tid + s];
    __syncthreads();
  }
  if (tid == 0) {
    atomicAdd(&d_out[2], red[0]);
    atomicAdd(&d_out[0], red[0]);
  }
}

// Merge the CS partial top-12 lists per row, gather edges, accumulate
// distance2_1 and the matched-edge count.
__global__ __launch_bounds__(256) void finalize_kernel(
    const float* __restrict__ latent_norm, const float* __restrict__ dist_X,
    const float* __restrict__ mask_X,
    const unsigned long long* __restrict__ topk_ws, float* __restrict__ d_out) {
  __shared__ float red[256];
  const int tid = threadIdx.x;
  const int gi = blockIdx.x * 256 + tid;
  const float invnorm = 1.0f / latent_norm[0];

  unsigned long long pk[KNN];
#pragma unroll
  for (int t = 0; t < KNN; ++t) pk[t] = SENTINEL;

  const unsigned long long* src = topk_ws + (size_t)gi * CS * KNN;
  for (int t = 0; t < CS * KNN; ++t) {
    unsigned long long cand = src[t];
    if (cand < pk[KNN - 1]) topk_insert(cand, pk);
  }

  float acc2 = 0.f, accc = 0.f;
#pragma unroll
  for (int t = 0; t < KNN; ++t) {
    unsigned j = (unsigned)(pk[t] & 0xFFFFFFFFull);
    float d2 = __uint_as_float((unsigned)(pk[t] >> 32));
    float dz = (d2 > 0.0f) ? sqrtf(d2) * invnorm : 0.0f;
    float dxv = dist_X[(size_t)gi * NPTS + j];
    float mxv = mask_X[(size_t)gi * NPTS + j];
    float diff = dxv - dz;
    acc2 += diff * diff;
    accc += mxv;  // Z-edge also present in X-mask
  }

  red[tid] = acc2;
  __syncthreads();
  for (int s = 128; s > 0; s >>= 1) {
    if (tid < s) red[tid] += red[tid + s];
    __syncthreads();
  }
  float racc2 = red[0];
  __syncthreads();
  red[tid] = accc;
  __syncthreads();
  for (int s = 128; s > 0; s >>= 1) {
    if (tid < s) red[tid] += red[tid + s];
    __syncthreads();
  }
  if (tid == 0) {
    atomicAdd(&d_out[3], racc2);
    atomicAdd(&d_out[0], racc2);
    atomicAdd(&d_out[1], red[0] * (1.0f / ((float)NPTS * (float)KNN)));
  }
}

extern "C" void kernel_launch(void* const* d_in, const int* in_sizes, int n_in,
                              void* d_out, int out_size, void* d_ws,
                              size_t ws_size, hipStream_t stream) {
  const float* latent      = (const float*)d_in[0];
  const float* latent_norm = (const float*)d_in[1];
  const float* dist_X      = (const float*)d_in[2];
  const float* mask_X      = (const float*)d_in[3];
  // d_in[4] = k (always 12; compiled in as KNN)
  float* out = (float*)d_out;

  float* sq = (float*)d_ws;                                   // 8192 floats
  unsigned long long* topk =
      (unsigned long long*)((char*)d_ws + NPTS * sizeof(float));  // 3.1 MB

  init_out<<<1, 64, 0, stream>>>(out);
  sq_kernel<<<NPTS / 256, 256, 0, stream>>>(latent, sq);
  dz_main<<<(NPTS / RT) * CS, 256, 0, stream>>>(latent, latent_norm, dist_X,
                                                mask_X, sq, topk, out);
  finalize_kernel<<<NPTS / 256, 256, 0, stream>>>(latent_norm, dist_X, mask_X,
                                                  topk, out);
}